// Round 4
// baseline (320.559 us; speedup 1.0000x reference)
//
#include <hip/hip_runtime.h>

#define HH 1024
#define WW 1024
#define NB 16
#define NROWS (NB * HH)          // 16384 flat rows (b*H + y)
#define NELEM ((long long)NROWS * WW)

// Load stencil window [x0-2 .. x0+5] of one row: aligned float2/float4/float2;
// edge lanes patch their pad zeros (matches reference zero-padding).
__device__ __forceinline__ void load_row(const float* __restrict__ rowp, int x0,
                                         bool ledge, bool redge,
                                         int offL, int offR, float w[8]) {
    float2 a = *(const float2*)(rowp + offL);
    float4 b = *(const float4*)(rowp + x0);
    float2 c = *(const float2*)(rowp + offR);
    if (ledge) { a.x = 0.f; a.y = 0.f; }
    if (redge) { c.x = 0.f; c.y = 0.f; }
    w[0]=a.x; w[1]=a.y; w[2]=b.x; w[3]=b.y; w[4]=b.z; w[5]=b.w; w[6]=c.x; w[7]=c.y;
}

__device__ __forceinline__ void zero_row(float w[8]) {
#pragma unroll
    for (int i = 0; i < 8; ++i) w[i] = 0.f;
}

__global__ __launch_bounds__(256) void closs_main(const float* __restrict__ yt,
                                                  const float* __restrict__ yp,
                                                  float* __restrict__ out) {
    // XCD-aware swizzle: consecutive blockIdx go to different XCDs (round-robin),
    // so give XCD i a contiguous 2048-row band. Rows r-2, r, r+2 then share one
    // XCD's L2 -> the 3x yp row reuse is served by that L2, not re-fetched
    // separately from L3/HBM by three different XCDs.
    const int bid = blockIdx.x;
    const int r   = ((bid & 7) << 11) | (bid >> 3);   // bijection on [0,16384)
    const int y   = r & (HH - 1);
    const int tid = threadIdx.x;
    const int x0  = tid << 2;
    const long long rowbase = (long long)r * WW;

    const bool ledge = (tid == 0);
    const bool redge = (tid == 255);
    const int offL = ledge ? x0 : (x0 - 2);
    const int offR = redge ? x0 : (x0 + 4);

    const float* pce = yp + rowbase;

    float A[8], B[8], C[8];   // rows y-2, y, y+2 windows
    load_row(pce, x0, ledge, redge, offL, offR, B);
    if (y >= 2) load_row(pce - 2 * WW, x0, ledge, redge, offL, offR, A);
    else        zero_row(A);
    if (y < HH - 2) load_row(pce + 2 * WW, x0, ledge, redge, offL, offR, C);
    else            zero_row(C);

    const float4 t4 = *(const float4*)(yt + rowbase + x0);
    const float tt[4] = {t4.x, t4.y, t4.z, t4.w};

    float sum = 0.f;
#pragma unroll
    for (int j = 0; j < 4; ++j) {
        const float c = B[j + 2];
        // max|c-nb| over 8 dilated neighbors = max(max(nb)-c, c-min(nb));
        // triples fold to v_max3/v_min3. Zero pads participate as 0 (== ref).
        const float mxA = fmaxf(fmaxf(A[j], A[j + 2]), A[j + 4]);
        const float mxB = fmaxf(B[j], B[j + 4]);
        const float mxC = fmaxf(fmaxf(C[j], C[j + 2]), C[j + 4]);
        const float mx  = fmaxf(fmaxf(mxA, mxB), mxC);
        const float mnA = fminf(fminf(A[j], A[j + 2]), A[j + 4]);
        const float mnB = fminf(B[j], B[j + 4]);
        const float mnC = fminf(fminf(C[j], C[j + 2]), C[j + 4]);
        const float mn  = fminf(fminf(mnA, mnB), mnC);
        const float w   = fmaxf(mx - c, c - mn);

        // log1p(-c) == log(1-c) exactly in fp32 for c in [0.5,1) (Sterbenz);
        // -100 clamp covers c -> 1 / c == 0. a = -(l1p + t*(lp-l1p)).
        const float lp  = fmaxf(__logf(c), -100.f);
        const float l1p = fmaxf(__logf(1.f - c), -100.f);
        const float th  = (c >= 0.5f) ? c : 0.f;
        sum += w * th - l1p - tt[j] * (lp - l1p);
    }

    // Block reduction: wave shfl (64 lanes) -> LDS -> one scaled atomicAdd.
    for (int o = 32; o > 0; o >>= 1) sum += __shfl_down(sum, o);
    __shared__ float wsum[4];
    if ((tid & 63) == 0) wsum[tid >> 6] = sum;
    __syncthreads();
    if (tid == 0) {
        const float total = wsum[0] + wsum[1] + wsum[2] + wsum[3];
        atomicAdd(out, total * (1.0f / (float)NELEM));
    }
}

extern "C" void kernel_launch(void* const* d_in, const int* in_sizes, int n_in,
                              void* d_out, int out_size, void* d_ws, size_t ws_size,
                              hipStream_t stream) {
    const float* y_true = (const float*)d_in[0];
    const float* y_pred = (const float*)d_in[1];
    float* out = (float*)d_out;

    // d_out is poisoned 0xAA before every launch; zero it for the atomics.
    hipMemsetAsync(out, 0, sizeof(float), stream);
    closs_main<<<NROWS, 256, 0, stream>>>(y_true, y_pred, out);
}

// Round 5
// 152.768 us; speedup vs baseline: 2.0983x; 2.0983x over previous
//
#include <hip/hip_runtime.h>

#define HH 1024
#define WW 1024
#define NB 16
#define NROWS (NB * HH)          // 16384 flat rows (b*H + y)
#define NELEM ((long long)NROWS * WW)

// Load stencil window [x0-2 .. x0+5] of one row: aligned float2/float4/float2;
// edge lanes patch their pad zeros (matches reference zero-padding).
__device__ __forceinline__ void load_row(const float* __restrict__ rowp, int x0,
                                         bool ledge, bool redge,
                                         int offL, int offR, float w[8]) {
    float2 a = *(const float2*)(rowp + offL);
    float4 b = *(const float4*)(rowp + x0);
    float2 c = *(const float2*)(rowp + offR);
    if (ledge) { a.x = 0.f; a.y = 0.f; }
    if (redge) { c.x = 0.f; c.y = 0.f; }
    w[0]=a.x; w[1]=a.y; w[2]=b.x; w[3]=b.y; w[4]=b.z; w[5]=b.w; w[6]=c.x; w[7]=c.y;
}

__device__ __forceinline__ void zero_row(float w[8]) {
#pragma unroll
    for (int i = 0; i < 8; ++i) w[i] = 0.f;
}

__global__ __launch_bounds__(256) void closs_main(const float* __restrict__ yt,
                                                  const float* __restrict__ yp,
                                                  float* __restrict__ partial) {
    // XCD-aware swizzle (validated in R4: FETCH 131->65 MB): consecutive
    // blockIdx round-robin across XCDs, so give XCD i a contiguous 2048-row
    // band; rows r-2, r, r+2 then share one XCD's L2.
    const int bid = blockIdx.x;
    const int r   = ((bid & 7) << 11) | (bid >> 3);   // bijection on [0,16384)
    const int y   = r & (HH - 1);
    const int tid = threadIdx.x;
    const int x0  = tid << 2;
    const long long rowbase = (long long)r * WW;

    const bool ledge = (tid == 0);
    const bool redge = (tid == 255);
    const int offL = ledge ? x0 : (x0 - 2);
    const int offR = redge ? x0 : (x0 + 4);

    const float* pce = yp + rowbase;

    float A[8], B[8], C[8];   // rows y-2, y, y+2 windows
    load_row(pce, x0, ledge, redge, offL, offR, B);
    if (y >= 2) load_row(pce - 2 * WW, x0, ledge, redge, offL, offR, A);
    else        zero_row(A);
    if (y < HH - 2) load_row(pce + 2 * WW, x0, ledge, redge, offL, offR, C);
    else            zero_row(C);

    const float4 t4 = *(const float4*)(yt + rowbase + x0);
    const float tt[4] = {t4.x, t4.y, t4.z, t4.w};

    float sum = 0.f;
#pragma unroll
    for (int j = 0; j < 4; ++j) {
        const float c = B[j + 2];
        // max|c-nb| over 8 dilated neighbors = max(max(nb)-c, c-min(nb));
        // bit-identical to direct |diff| chain (verified absmax 0.0 in R4);
        // triples fold to v_max3/v_min3. Zero pads participate as 0 (== ref).
        const float mxA = fmaxf(fmaxf(A[j], A[j + 2]), A[j + 4]);
        const float mxB = fmaxf(B[j], B[j + 4]);
        const float mxC = fmaxf(fmaxf(C[j], C[j + 2]), C[j + 4]);
        const float mx  = fmaxf(fmaxf(mxA, mxB), mxC);
        const float mnA = fminf(fminf(A[j], A[j + 2]), A[j + 4]);
        const float mnB = fminf(B[j], B[j + 4]);
        const float mnC = fminf(fminf(C[j], C[j + 2]), C[j + 4]);
        const float mn  = fminf(fminf(mnA, mnB), mnC);
        const float w   = fmaxf(mx - c, c - mn);

        // log1p(-c) == log(1-c) exactly in fp32 for c in [0.5,1) (Sterbenz);
        // -100 clamp covers c -> 1 / c == 0. a = -(l1p + t*(lp-l1p)).
        const float lp  = fmaxf(__logf(c), -100.f);
        const float l1p = fmaxf(__logf(1.f - c), -100.f);
        const float th  = (c >= 0.5f) ? c : 0.f;
        sum += w * th - l1p - tt[j] * (lp - l1p);
    }

    // Block reduction: wave shfl (64 lanes) -> LDS -> one partial write.
    // NO atomics: R4 showed 16384 same-address atomicAdds serialize to ~215 us.
    for (int o = 32; o > 0; o >>= 1) sum += __shfl_down(sum, o);
    __shared__ float wsum[4];
    if ((tid & 63) == 0) wsum[tid >> 6] = sum;
    __syncthreads();
    if (tid == 0) partial[r] = wsum[0] + wsum[1] + wsum[2] + wsum[3];
}

// Final reduction over 16384 partials in one 1024-thread block; float4 loads
// give 4 independent in-flight loads per thread. Second dispatch is free in
// the graph (R2 vs R3 totals were identical).
__global__ __launch_bounds__(1024) void closs_reduce(const float* __restrict__ partial,
                                                     float* __restrict__ out) {
    const float4* p4 = (const float4*)partial;   // 4096 float4s
    float s = 0.f;
#pragma unroll
    for (int i = 0; i < 4; ++i) {
        float4 v = p4[threadIdx.x + (i << 10)];
        s += (v.x + v.y) + (v.z + v.w);
    }
    for (int o = 32; o > 0; o >>= 1) s += __shfl_down(s, o);
    __shared__ float wsum[16];
    if ((threadIdx.x & 63) == 0) wsum[threadIdx.x >> 6] = s;
    __syncthreads();
    if (threadIdx.x == 0) {
        float t = 0.f;
#pragma unroll
        for (int i = 0; i < 16; ++i) t += wsum[i];
        out[0] = t * (1.0f / (float)NELEM);
    }
}

extern "C" void kernel_launch(void* const* d_in, const int* in_sizes, int n_in,
                              void* d_out, int out_size, void* d_ws, size_t ws_size,
                              hipStream_t stream) {
    const float* y_true = (const float*)d_in[0];
    const float* y_pred = (const float*)d_in[1];
    float* out = (float*)d_out;
    float* partial = (float*)d_ws;   // NROWS*4 = 64 KB scratch

    closs_main<<<NROWS, 256, 0, stream>>>(y_true, y_pred, partial);
    closs_reduce<<<1, 1024, 0, stream>>>(partial, out);
}

// Round 6
// 146.811 us; speedup vs baseline: 2.1835x; 1.0406x over previous
//
#include <hip/hip_runtime.h>

#define HH 1024
#define WW 1024
#define NB 16
#define NROWS (NB * HH)           // 16384 flat rows (b*H + y)
#define NELEM ((long long)NROWS * WW)
#define NBLK (NROWS / 2)          // 8192 blocks, 2 rows per block

// Load stencil window [x0-2 .. x0+9] (12 elems for 8 outputs) of one row.
// All pieces naturally aligned: float2 @ x0-2 (8B-aligned since x0 % 8 == 0),
// float4 @ x0, float4 @ x0+4, float2 @ x0+8. Edge lanes clamp the halo
// address in-bounds and patch zeros (matches reference zero padding).
__device__ __forceinline__ void load_win(const float* __restrict__ p, int x0,
                                         bool ledge, bool redge, float w[12]) {
    float2 L  = *(const float2*)(p + (ledge ? x0 : x0 - 2));
    float4 M0 = *(const float4*)(p + x0);
    float4 M1 = *(const float4*)(p + x0 + 4);
    float2 R  = *(const float2*)(p + (redge ? x0 : x0 + 8));
    if (ledge) { L.x = 0.f; L.y = 0.f; }
    if (redge) { R.x = 0.f; R.y = 0.f; }
    w[0]=L.x;  w[1]=L.y;
    w[2]=M0.x; w[3]=M0.y; w[4]=M0.z; w[5]=M0.w;
    w[6]=M1.x; w[7]=M1.y; w[8]=M1.z; w[9]=M1.w;
    w[10]=R.x; w[11]=R.y;
}

__device__ __forceinline__ void zero_win(float w[12]) {
#pragma unroll
    for (int i = 0; i < 12; ++i) w[i] = 0.f;
}

__global__ __launch_bounds__(256) void closs_main(const float* __restrict__ yt,
                                                  const float* __restrict__ yp,
                                                  float* __restrict__ partial) {
    const int tid = threadIdx.x;
    const int rh  = tid >> 7;               // row-half 0/1 (wave-uniform: waves 0,1 vs 2,3)
    const int cth = tid & 127;              // column-thread within the row
    const int x0  = cth << 3;               // 8 consecutive elements per thread
    const int r   = (blockIdx.x << 1) | rh; // flat row
    const int y   = r & (HH - 1);
    const int rowoff = r * WW;              // max 16M-1K, fits int

    const bool ledge = (cth == 0);
    const bool redge = (cth == 127);

    const float* pce = yp + rowoff;

    float U[12], Ce[12], D[12];             // rows y-2, y, y+2 windows
    load_win(pce, x0, ledge, redge, Ce);
    if (y >= 2)      load_win(pce - 2 * WW, x0, ledge, redge, U);
    else             zero_win(U);
    if (y < HH - 2)  load_win(pce + 2 * WW, x0, ledge, redge, D);
    else             zero_win(D);

    const float4 t0 = *(const float4*)(yt + rowoff + x0);
    const float4 t1 = *(const float4*)(yt + rowoff + x0 + 4);
    const float tt[8] = {t0.x, t0.y, t0.z, t0.w, t1.x, t1.y, t1.z, t1.w};

    float sum = 0.f;
#pragma unroll
    for (int j = 0; j < 8; ++j) {
        const float c = Ce[j + 2];
        // max|c-nb| over 8 dilated neighbors = max(max(nb)-c, c-min(nb));
        // bit-identical to the |diff| chain (absmax 0.0 since R3); fmax/fmin
        // triples fold to v_max3/v_min3. Zero pads participate as 0 (== ref).
        const float mxA = fmaxf(fmaxf(U[j], U[j + 2]), U[j + 4]);
        const float mxB = fmaxf(Ce[j], Ce[j + 4]);
        const float mxC = fmaxf(fmaxf(D[j], D[j + 2]), D[j + 4]);
        const float mx  = fmaxf(fmaxf(mxA, mxB), mxC);
        const float mnA = fminf(fminf(U[j], U[j + 2]), U[j + 4]);
        const float mnB = fminf(Ce[j], Ce[j + 4]);
        const float mnC = fminf(fminf(D[j], D[j + 2]), D[j + 4]);
        const float mn  = fminf(fminf(mnA, mnB), mnC);
        const float w   = fmaxf(mx - c, c - mn);

        // log1p(-c) == log(1-c) exactly in fp32 for c in [0.5,1) (Sterbenz);
        // -100 clamp covers c -> 1 / c == 0. a = -(l1p + t*(lp-l1p)).
        const float lp  = fmaxf(__logf(c), -100.f);
        const float l1p = fmaxf(__logf(1.f - c), -100.f);
        const float th  = (c >= 0.5f) ? c : 0.f;
        sum += w * th - l1p - tt[j] * (lp - l1p);
    }

    // Block reduction: wave shfl (64 lanes) -> LDS -> one partial write.
    // No atomics (R4: 16384 same-address atomicAdds serialize to ~215 us).
    for (int o = 32; o > 0; o >>= 1) sum += __shfl_down(sum, o);
    __shared__ float wsum[4];
    if ((tid & 63) == 0) wsum[tid >> 6] = sum;
    __syncthreads();
    if (tid == 0) partial[blockIdx.x] = wsum[0] + wsum[1] + wsum[2] + wsum[3];
}

// Final reduction over 8192 partials in one 1024-thread block.
__global__ __launch_bounds__(1024) void closs_reduce(const float* __restrict__ partial,
                                                     float* __restrict__ out) {
    const float4* p4 = (const float4*)partial;   // 2048 float4s
    float s = 0.f;
#pragma unroll
    for (int i = 0; i < 2; ++i) {
        float4 v = p4[threadIdx.x + (i << 10)];
        s += (v.x + v.y) + (v.z + v.w);
    }
    for (int o = 32; o > 0; o >>= 1) s += __shfl_down(s, o);
    __shared__ float wsum[16];
    if ((threadIdx.x & 63) == 0) wsum[threadIdx.x >> 6] = s;
    __syncthreads();
    if (threadIdx.x == 0) {
        float t = 0.f;
#pragma unroll
        for (int i = 0; i < 16; ++i) t += wsum[i];
        out[0] = t * (1.0f / (float)NELEM);
    }
}

extern "C" void kernel_launch(void* const* d_in, const int* in_sizes, int n_in,
                              void* d_out, int out_size, void* d_ws, size_t ws_size,
                              hipStream_t stream) {
    const float* y_true = (const float*)d_in[0];
    const float* y_pred = (const float*)d_in[1];
    float* out = (float*)d_out;
    float* partial = (float*)d_ws;   // NBLK*4 = 32 KB scratch

    closs_main<<<NBLK, 256, 0, stream>>>(y_true, y_pred, partial);
    closs_reduce<<<1, 1024, 0, stream>>>(partial, out);
}

// Round 7
// 146.492 us; speedup vs baseline: 2.1882x; 1.0022x over previous
//
#include <hip/hip_runtime.h>

#define HH 1024
#define WW 1024
#define NB 16
#define TR 8                        // output rows per block
#define SR (TR + 4)                 // staged rows: y0-2 .. y0+TR+1
#define NBLK (NB * (HH / TR))       // 2048 blocks
#define NELEM ((long long)NB * HH * WW)

// Read an 8-float stencil window [c0-2 .. c0+5] from an LDS row.
// Lane stride is 16 B -> 2 lanes/bank on all pieces = conflict-free (m136).
__device__ __forceinline__ void lds_win(const float* __restrict__ S, int row,
                                        int c0, bool ledge, bool redge, float w[8]) {
    const float* p = S + row * WW;
    float2 L = *(const float2*)(p + (ledge ? c0 : c0 - 2));
    float4 M = *(const float4*)(p + c0);
    float2 R = *(const float2*)(p + (redge ? c0 : c0 + 4));
    if (ledge) { L.x = 0.f; L.y = 0.f; }
    if (redge) { R.x = 0.f; R.y = 0.f; }
    w[0]=L.x; w[1]=L.y; w[2]=M.x; w[3]=M.y; w[4]=M.z; w[5]=M.w; w[6]=R.x; w[7]=R.y;
}

__global__ __launch_bounds__(256) void closs_main(const float* __restrict__ yt,
                                                  const float* __restrict__ yp,
                                                  float* __restrict__ partial) {
    __shared__ float S[SR * WW];        // 48 KB -> 3 blocks/CU resident

    const int bid  = blockIdx.x;
    const int img  = bid >> 7;          // 128 tiles per image
    const int tile = bid & 127;
    const int y0   = tile * TR;
    const int tid  = threadIdx.x;
    const int c0   = tid << 2;          // 4 columns per thread

    const float* __restrict__ ybase = yp + (long long)img * (HH * WW);
    const float* __restrict__ tbase = yt + ((long long)img * HH + y0) * WW;

    // Stage SR contiguous rows as pure aligned float4 streams (the untried
    // axis: long sequential reads, each global byte touched once per tile).
    // Rows outside [0,HH) zero-filled == reference zero padding. Block-uniform
    // branch, no divergence.
#pragma unroll
    for (int i = 0; i < SR; ++i) {
        const int gy = y0 - 2 + i;
        float4 v = make_float4(0.f, 0.f, 0.f, 0.f);
        if (gy >= 0 && gy < HH)
            v = *(const float4*)(ybase + gy * WW + c0);
        *(float4*)&S[i * WW + c0] = v;
    }
    __syncthreads();

    const bool ledge = (tid == 0);
    const bool redge = (tid == 255);

    float sum = 0.f;
#pragma unroll
    for (int k = 0; k < TR; ++k) {
        float A[8], B[8], C[8];         // LDS rows k (y-2), k+2 (y), k+4 (y+2)
        lds_win(S, k,     c0, ledge, redge, A);
        lds_win(S, k + 2, c0, ledge, redge, B);
        lds_win(S, k + 4, c0, ledge, redge, C);

        const float4 t4 = *(const float4*)(tbase + k * WW + c0);
        const float tt[4] = {t4.x, t4.y, t4.z, t4.w};

#pragma unroll
        for (int j = 0; j < 4; ++j) {
            const float c = B[j + 2];
            // max|c-nb| = max(max(nb)-c, c-min(nb)); bit-identical to the
            // |diff| chain (absmax 0.0 since R3); folds to v_max3/v_min3.
            const float mxA = fmaxf(fmaxf(A[j], A[j + 2]), A[j + 4]);
            const float mxB = fmaxf(B[j], B[j + 4]);
            const float mxC = fmaxf(fmaxf(C[j], C[j + 2]), C[j + 4]);
            const float mx  = fmaxf(fmaxf(mxA, mxB), mxC);
            const float mnA = fminf(fminf(A[j], A[j + 2]), A[j + 4]);
            const float mnB = fminf(B[j], B[j + 4]);
            const float mnC = fminf(fminf(C[j], C[j + 2]), C[j + 4]);
            const float mn  = fminf(fminf(mnA, mnB), mnC);
            const float w   = fmaxf(mx - c, c - mn);

            // log1p(-c) == log(1-c) exactly in fp32 for c in [0.5,1)
            // (Sterbenz); -100 clamp covers c -> 1 / c == 0.
            const float lp  = fmaxf(__logf(c), -100.f);
            const float l1p = fmaxf(__logf(1.f - c), -100.f);
            const float th  = (c >= 0.5f) ? c : 0.f;
            sum += w * th - l1p - tt[j] * (lp - l1p);
        }
    }

    // Block reduction -> one partial write (no atomics: R4 proved 16K
    // same-address atomicAdds serialize to ~215 us).
    for (int o = 32; o > 0; o >>= 1) sum += __shfl_down(sum, o);
    __shared__ float wsum[4];
    if ((tid & 63) == 0) wsum[tid >> 6] = sum;
    __syncthreads();
    if (tid == 0) partial[bid] = wsum[0] + wsum[1] + wsum[2] + wsum[3];
}

// Final reduction over 2048 partials in one 1024-thread block.
__global__ __launch_bounds__(1024) void closs_reduce(const float* __restrict__ partial,
                                                     float* __restrict__ out) {
    const float2* p2 = (const float2*)partial;    // 1024 float2s
    float2 v = p2[threadIdx.x];
    float s = v.x + v.y;
    for (int o = 32; o > 0; o >>= 1) s += __shfl_down(s, o);
    __shared__ float wsum[16];
    if ((threadIdx.x & 63) == 0) wsum[threadIdx.x >> 6] = s;
    __syncthreads();
    if (threadIdx.x == 0) {
        float t = 0.f;
#pragma unroll
        for (int i = 0; i < 16; ++i) t += wsum[i];
        out[0] = t * (1.0f / (float)NELEM);
    }
}

extern "C" void kernel_launch(void* const* d_in, const int* in_sizes, int n_in,
                              void* d_out, int out_size, void* d_ws, size_t ws_size,
                              hipStream_t stream) {
    const float* y_true = (const float*)d_in[0];
    const float* y_pred = (const float*)d_in[1];
    float* out = (float*)d_out;
    float* partial = (float*)d_ws;   // NBLK*4 = 8 KB scratch

    closs_main<<<NBLK, 256, 0, stream>>>(y_true, y_pred, partial);
    closs_reduce<<<1, 1024, 0, stream>>>(partial, out);
}